// Round 4
// baseline (418.076 us; speedup 1.0000x reference)
//
#include <hip/hip_runtime.h>

#define N_PROT 8192
#define E_PP   163840
#define E_LP   81920
#define NW0    (E_PP / 32)   // 5120 pp wave-groups
#define NW1    (E_LP / 32)   // 2560 lp wave-groups

typedef float        f32x4  __attribute__((ext_vector_type(4)));
typedef float        f32x16 __attribute__((ext_vector_type(16)));
typedef unsigned int u32x4  __attribute__((ext_vector_type(4)));
typedef short        s16x8  __attribute__((ext_vector_type(8)));
typedef unsigned short ushort_t;

union frag32 { u32x4 v; s16x8 s; };

__device__ inline unsigned short f2bf(float f) {
  unsigned int u = __float_as_uint(f);
  u = u + 0x7FFFu + ((u >> 16) & 1u);   // RTNE
  return (unsigned short)(u >> 16);
}

__device__ inline unsigned int cvt_pk_bf16(float lo, float hi) {
  unsigned int r;
  asm("v_cvt_pk_bf16_f32 %0, %1, %2" : "=v"(r) : "v"(lo), "v"(hi));
  return r;
}

__device__ inline float gelu_tanh(float x) {
  const float c0 = 0.7978845608028654f;
  float inner = c0 * (x + 0.044715f * x * x * x);
  return 0.5f * x * (1.0f + tanhf(inner));
}

// ---------------------------------------------------------------------------
// Pre-transpose weights [K][128]+[K][128] -> k-inner bf16 [K/8][256][8]
// ---------------------------------------------------------------------------
__global__ void build_bt(const float* __restrict__ Watt, const float* __restrict__ Wval,
                         ushort_t* __restrict__ Bt, int K)
{
  int i = blockIdx.x * 256 + threadIdx.x;
  if (i >= K * 256) return;
  int k = i >> 8, n = i & 255;
  float v = (n < 128) ? Watt[(size_t)k * 128 + n] : Wval[(size_t)k * 128 + (n - 128)];
  Bt[(size_t)(k >> 3) * 2048 + n * 8 + (k & 7)] = f2bf(v);
}

// ---------------------------------------------------------------------------
// Edge GATv2, barrier-free: one wave owns 32 edges x 256 cols.
// A fragments loaded global->reg (imm offsets), B fragments from L2-resident
// Bt (k-inner layout). v_mfma_f32_32x32x16_bf16, acc = 8 x f32x16.
// Epilogue: butterfly-allreduce logits (every lane ends holding exp() for
// exactly the rows it owns in the C-layout), then value atomics.
// MODE 0: pp (z = [src_exp(448) | prot[sink](128)]), K=576
// MODE 1: lp (z = [lig[src](128) | prot[sink](128) | eattr(128)]), K=384
// ---------------------------------------------------------------------------
template<int MODE>
__device__ __forceinline__ void edge_wave32(
    int wg,
    const float* __restrict__ Afeat, const float* __restrict__ prot,
    const float* __restrict__ eattr, const int* __restrict__ eidx,
    const ushort_t* __restrict__ Bt,
    const float* __restrict__ batt, const float* __restrict__ avec,
    const float* __restrict__ bval,
    float* __restrict__ num, float* __restrict__ den)
{
  constexpr int K  = (MODE == 0) ? 576 : 384;
  constexpr int E  = (MODE == 0) ? E_PP : E_LP;
  constexpr int NT = K / 16;

  const int lane = threadIdx.x & 63;
  const int col  = lane & 31;         // edge row (A) / output col (B,C)
  const int hi   = lane >> 5;         // k-group selector
  const int e0   = wg * 32;
  const int eid  = e0 + col;
  const int snk  = eidx[E + eid];

  // per-lane B base: Bt byte addr = (k0/8 + hi)*4096 + n*16, n = nb*32 + col
  const char* bbase = (const char*)Bt + hi * 4096 + col * 16;

  // A bases (8 contiguous floats per lane per step, imm offsets off these)
  const f32x4* aA;
  const f32x4* aP;
  const f32x4* aE = nullptr;
  if (MODE == 0) {
    aA = (const f32x4*)(Afeat + (size_t)eid * 448) + hi * 2;
    aP = (const f32x4*)(prot  + (size_t)snk * 128) + hi * 2;
  } else {
    aA = (const f32x4*)(Afeat + (size_t)eidx[eid] * 128) + hi * 2;
    aP = (const f32x4*)(prot  + (size_t)snk * 128) + hi * 2;
    aE = (const f32x4*)(eattr + (size_t)eid * 128) + hi * 2;
  }

  f32x16 acc[8];
  #pragma unroll
  for (int i = 0; i < 8; ++i)
    acc[i] = (f32x16)(0.0f);

  #pragma unroll
  for (int s = 0; s < NT; ++s) {
    const int k0 = s * 16;
    const f32x4* ap;
    if (MODE == 0) {
      ap = (k0 < 448) ? (aA + (k0 >> 2)) : (aP + ((k0 - 448) >> 2));
    } else {
      const int r = k0 >> 7, kk = (k0 & 127) >> 2;
      ap = (r == 0) ? (aA + kk) : (r == 1) ? (aP + kk) : (aE + kk);
    }
    const f32x4 u0 = ap[0];
    const f32x4 u1 = ap[1];
    frag32 af;
    af.v[0] = cvt_pk_bf16(u0.x, u0.y);
    af.v[1] = cvt_pk_bf16(u0.z, u0.w);
    af.v[2] = cvt_pk_bf16(u1.x, u1.y);
    af.v[3] = cvt_pk_bf16(u1.z, u1.w);

    const char* bs = bbase + (size_t)s * 8192;
    #pragma unroll
    for (int nb = 0; nb < 8; ++nb) {
      frag32 bf;
      bf.v = *(const u32x4*)(bs + nb * 512);
      acc[nb] = __builtin_amdgcn_mfma_f32_32x32x16_bf16(af.s, bf.s, acc[nb], 0, 0, 0);
    }
  }

  // sink node of C-row (r,hi) — lane (row) holds its own snk
  int snkr[16];
  #pragma unroll
  for (int r = 0; r < 16; ++r)
    snkr[r] = __shfl(snk, (r & 3) + 8 * (r >> 2) + 4 * hi, 64);

  // ---- attention logits: head h = att col-tile h (cols h*32..h*32+31) ----
  float ep[4][16];
  #pragma unroll
  for (int h = 0; h < 4; ++h) {
    const float bt_ = batt[h * 32 + col];
    const float av_ = avec[h * 32 + col];
    #pragma unroll
    for (int r = 0; r < 16; ++r) {
      float x = acc[h][r] + bt_;
      x = (x > 0.f) ? x : 0.2f * x;
      float p = x * av_;
      p += __shfl_xor(p, 1, 64);
      p += __shfl_xor(p, 2, 64);
      p += __shfl_xor(p, 4, 64);
      p += __shfl_xor(p, 8, 64);
      p += __shfl_xor(p, 16, 64);          // allreduce within each 32-half
      const float e = __expf(p);           // no max-sub: logits bounded (~|6|)
      ep[h][r] = e;
      if (col == 0)                        // lanes 0 and 32: two distinct rows
        atomicAdd(&den[(size_t)snkr[r] * 4 + h], e);
    }
  }

  // ---- value accumulation: val col-tile h (cols 128+h*32 ..) ----
  #pragma unroll
  for (int h = 0; h < 4; ++h) {
    const float bv_ = bval[h * 32 + col];
    #pragma unroll
    for (int r = 0; r < 16; ++r) {
      const float v = (acc[4 + h][r] + bv_) * ep[h][r];
      atomicAdd(&num[(size_t)snkr[r] * 128 + h * 32 + col], v);
    }
  }
}

__global__ __launch_bounds__(256, 2)
void edge_gat2(const float* __restrict__ src_exp, const float* __restrict__ prot,
               const float* __restrict__ lig, const float* __restrict__ eattr,
               const int* __restrict__ eidx0, const int* __restrict__ eidx1,
               const ushort_t* __restrict__ Bt0, const ushort_t* __restrict__ Bt1,
               const float* __restrict__ batt0, const float* __restrict__ a0,
               const float* __restrict__ bval0,
               const float* __restrict__ batt1, const float* __restrict__ a1,
               const float* __restrict__ bval1,
               float* __restrict__ num0, float* __restrict__ den0,
               float* __restrict__ num1, float* __restrict__ den1)
{
  const int wg = blockIdx.x * 4 + (threadIdx.x >> 6);
  if (wg < NW0)
    edge_wave32<0>(wg, src_exp, prot, nullptr, eidx0, Bt0,
                   batt0, a0, bval0, num0, den0);
  else
    edge_wave32<1>(wg - NW0, lig, prot, eattr, eidx1, Bt1,
                   batt1, a1, bval1, num1, den1);
}

// ---------------------------------------------------------------------------
// LN over 16 rows of 128 (4 waves; wave handles 4 rows, 16 lanes x 8 cols)
// ---------------------------------------------------------------------------
__device__ inline void ln_rows16(const float* __restrict__ src, float* __restrict__ dst,
                                 const float* __restrict__ g, const float* __restrict__ b,
                                 const int t)
{
  const int lane = t & 63;
  const int n    = (t >> 6) * 4 + (lane >> 4);
  const int c0   = (lane & 15) * 8;
  f32x4 va = *(const f32x4*)&src[n * 128 + c0];
  f32x4 vb = *(const f32x4*)&src[n * 128 + c0 + 4];
  float s = va.x + va.y + va.z + va.w + vb.x + vb.y + vb.z + vb.w;
  float q = va.x * va.x + va.y * va.y + va.z * va.z + va.w * va.w
          + vb.x * vb.x + vb.y * vb.y + vb.z * vb.z + vb.w * vb.w;
  #pragma unroll
  for (int m = 1; m < 16; m <<= 1) {
    s += __shfl_xor(s, m, 64);
    q += __shfl_xor(q, m, 64);
  }
  const float mean = s * 0.0078125f;
  const float var  = q * 0.0078125f - mean * mean;
  const float r    = rsqrtf(var + 1e-5f);
  f32x4 oa, ob;
  oa.x = (va.x - mean) * r * g[c0 + 0] + b[c0 + 0];
  oa.y = (va.y - mean) * r * g[c0 + 1] + b[c0 + 1];
  oa.z = (va.z - mean) * r * g[c0 + 2] + b[c0 + 2];
  oa.w = (va.w - mean) * r * g[c0 + 3] + b[c0 + 3];
  ob.x = (vb.x - mean) * r * g[c0 + 4] + b[c0 + 4];
  ob.y = (vb.y - mean) * r * g[c0 + 5] + b[c0 + 5];
  ob.z = (vb.z - mean) * r * g[c0 + 6] + b[c0 + 6];
  ob.w = (vb.w - mean) * r * g[c0 + 7] + b[c0 + 7];
  *(f32x4*)&dst[n * 128 + c0]     = oa;
  *(f32x4*)&dst[n * 128 + c0 + 4] = ob;
}

// ---------------------------------------------------------------------------
// Fused node update: attn combine -> MLP(128->128->128) -> LN1 ->
//                    MLP(128->512->128) -> LN2  (16 nodes per block)
// ---------------------------------------------------------------------------
__global__ __launch_bounds__(256)
void node_mlp(const float* __restrict__ num0, const float* __restrict__ den0,
              const float* __restrict__ num1, const float* __restrict__ den1,
              const float* __restrict__ prot,
              const float* __restrict__ Wh1, const float* __restrict__ bh1,
              const float* __restrict__ Wh2, const float* __restrict__ bh2,
              const float* __restrict__ ln1g, const float* __restrict__ ln1b,
              const float* __restrict__ Wm1, const float* __restrict__ bm1,
              const float* __restrict__ Wm2, const float* __restrict__ bm2,
              const float* __restrict__ ln2g, const float* __restrict__ ln2b,
              float* __restrict__ out)
{
  __shared__ float xs[16 * 128];
  __shared__ float sc[16 * 512];
  const int t    = threadIdx.x;
  const int m0   = blockIdx.x * 16;
  const int c    = t & 127;
  const int half = t >> 7;

  for (int idx = t; idx < 2048; idx += 256) {
    const int n = idx >> 7, cc = idx & 127;
    const int g = m0 + n, hd = cc >> 5;
    const float a0v = num0[(size_t)g * 128 + cc] / (den0[g * 4 + hd] + 1e-9f);
    const float a1v = num1[(size_t)g * 128 + cc] / (den1[g * 4 + hd] + 1e-9f);
    sc[idx] = a0v + a1v;
  }
  __syncthreads();

  {
    float a[8] = {0, 0, 0, 0, 0, 0, 0, 0};
    for (int k = 0; k < 128; k += 4) {
      const float w0 = Wh1[(k + 0) * 128 + c];
      const float w1 = Wh1[(k + 1) * 128 + c];
      const float w2 = Wh1[(k + 2) * 128 + c];
      const float w3 = Wh1[(k + 3) * 128 + c];
      #pragma unroll
      for (int i = 0; i < 8; ++i) {
        const f32x4 xv = *(const f32x4*)&sc[(half * 8 + i) * 128 + k];
        a[i] = fmaf(xv.w, w3, fmaf(xv.z, w2, fmaf(xv.y, w1, fmaf(xv.x, w0, a[i]))));
      }
    }
    const float bb = bh1[c];
    #pragma unroll
    for (int i = 0; i < 8; ++i)
      sc[2048 + (half * 8 + i) * 128 + c] = gelu_tanh(a[i] + bb);
  }
  __syncthreads();

  {
    float a[8] = {0, 0, 0, 0, 0, 0, 0, 0};
    for (int k = 0; k < 128; k += 4) {
      const float w0 = Wh2[(k + 0) * 128 + c];
      const float w1 = Wh2[(k + 1) * 128 + c];
      const float w2 = Wh2[(k + 2) * 128 + c];
      const float w3 = Wh2[(k + 3) * 128 + c];
      #pragma unroll
      for (int i = 0; i < 8; ++i) {
        const f32x4 xv = *(const f32x4*)&sc[2048 + (half * 8 + i) * 128 + k];
        a[i] = fmaf(xv.w, w3, fmaf(xv.z, w2, fmaf(xv.y, w1, fmaf(xv.x, w0, a[i]))));
      }
    }
    const float bb = bh2[c];
    #pragma unroll
    for (int i = 0; i < 8; ++i) {
      const int n = half * 8 + i;
      xs[n * 128 + c] = a[i] + bb + prot[(size_t)(m0 + n) * 128 + c];
    }
  }
  __syncthreads();
  ln_rows16(xs, xs, ln1g, ln1b, t);
  __syncthreads();

  {
    float a0[16], a1[16];
    #pragma unroll
    for (int i = 0; i < 16; ++i) { a0[i] = 0.f; a1[i] = 0.f; }
    for (int k = 0; k < 128; k += 4) {
      const float u0 = Wm1[(size_t)(k + 0) * 512 + t];
      const float u1 = Wm1[(size_t)(k + 1) * 512 + t];
      const float u2 = Wm1[(size_t)(k + 2) * 512 + t];
      const float u3 = Wm1[(size_t)(k + 3) * 512 + t];
      const float v0 = Wm1[(size_t)(k + 0) * 512 + t + 256];
      const float v1 = Wm1[(size_t)(k + 1) * 512 + t + 256];
      const float v2 = Wm1[(size_t)(k + 2) * 512 + t + 256];
      const float v3 = Wm1[(size_t)(k + 3) * 512 + t + 256];
      #pragma unroll
      for (int i = 0; i < 16; ++i) {
        const f32x4 xv = *(const f32x4*)&xs[i * 128 + k];
        a0[i] = fmaf(xv.w, u3, fmaf(xv.z, u2, fmaf(xv.y, u1, fmaf(xv.x, u0, a0[i]))));
        a1[i] = fmaf(xv.w, v3, fmaf(xv.z, v2, fmaf(xv.y, v1, fmaf(xv.x, v0, a1[i]))));
      }
    }
    const float bb0 = bm1[t], bb1 = bm1[t + 256];
    #pragma unroll
    for (int i = 0; i < 16; ++i) {
      sc[i * 512 + t]       = gelu_tanh(a0[i] + bb0);
      sc[i * 512 + t + 256] = gelu_tanh(a1[i] + bb1);
    }
  }
  __syncthreads();

  {
    float a[8] = {0, 0, 0, 0, 0, 0, 0, 0};
    for (int k = 0; k < 512; k += 4) {
      const float w0 = Wm2[(size_t)(k + 0) * 128 + c];
      const float w1 = Wm2[(size_t)(k + 1) * 128 + c];
      const float w2 = Wm2[(size_t)(k + 2) * 128 + c];
      const float w3 = Wm2[(size_t)(k + 3) * 128 + c];
      #pragma unroll
      for (int i = 0; i < 8; ++i) {
        const f32x4 tv = *(const f32x4*)&sc[(half * 8 + i) * 512 + k];
        a[i] = fmaf(tv.w, w3, fmaf(tv.z, w2, fmaf(tv.y, w1, fmaf(tv.x, w0, a[i]))));
      }
    }
    __syncthreads();
    const float bb = bm2[c];
    #pragma unroll
    for (int i = 0; i < 8; ++i) {
      const int n = half * 8 + i;
      sc[n * 128 + c] = a[i] + bb + xs[n * 128 + c];
    }
  }
  __syncthreads();
  ln_rows16(sc, out + (size_t)m0 * 128, ln2g, ln2b, t);
}

// ---------------------------------------------------------------------------
extern "C" void kernel_launch(void* const* d_in, const int* in_sizes, int n_in,
                              void* d_out, int out_size, void* d_ws, size_t ws_size,
                              hipStream_t stream)
{
  const float* src_exp = (const float*)d_in[0];
  const float* prot    = (const float*)d_in[1];
  const float* pvec    = (const float*)d_in[2];
  const int*   eidx0   = (const int*)d_in[3];
  const float* lig     = (const float*)d_in[4];
  const float* eattr   = (const float*)d_in[5];
  const int*   eidx1   = (const int*)d_in[6];
  const float* Watt0 = (const float*)d_in[7];
  const float* batt0 = (const float*)d_in[8];
  const float* a0    = (const float*)d_in[9];
  const float* Wval0 = (const float*)d_in[10];
  const float* bval0 = (const float*)d_in[11];
  const float* Watt1 = (const float*)d_in[12];
  const float* batt1 = (const float*)d_in[13];
  const float* a1    = (const float*)d_in[14];
  const float* Wval1 = (const float*)d_in[15];
  const float* bval1 = (const float*)d_in[16];
  const float* Wh1  = (const float*)d_in[17];
  const float* bh1  = (const float*)d_in[18];
  const float* Wh2  = (const float*)d_in[19];
  const float* bh2  = (const float*)d_in[20];
  const float* ln1g = (const float*)d_in[21];
  const float* ln1b = (const float*)d_in[22];
  const float* Wm1  = (const float*)d_in[23];
  const float* bm1  = (const float*)d_in[24];
  const float* Wm2  = (const float*)d_in[25];
  const float* bm2  = (const float*)d_in[26];
  const float* ln2g = (const float*)d_in[27];
  const float* ln2b = (const float*)d_in[28];

  float* num0 = (float*)d_ws;
  float* num1 = num0 + (size_t)N_PROT * 128;
  float* den0 = num1 + (size_t)N_PROT * 128;
  float* den1 = den0 + (size_t)N_PROT * 4;
  ushort_t* Bt0 = (ushort_t*)(den1 + (size_t)N_PROT * 4);
  ushort_t* Bt1 = Bt0 + 576 * 256;

  hipMemsetAsync(d_ws, 0, ((size_t)N_PROT * 128 * 2 + (size_t)N_PROT * 8) * sizeof(float), stream);

  build_bt<<<(576 * 256) / 256, 256, 0, stream>>>(Watt0, Wval0, Bt0, 576);
  build_bt<<<(384 * 256) / 256, 256, 0, stream>>>(Watt1, Wval1, Bt1, 384);

  edge_gat2<<<(NW0 + NW1) / 4, 256, 0, stream>>>(
      src_exp, prot, lig, eattr, eidx0, eidx1, Bt0, Bt1,
      batt0, a0, bval0, batt1, a1, bval1, num0, den0, num1, den1);

  node_mlp<<<N_PROT / 16, 256, 0, stream>>>(num0, den0, num1, den1, prot,
                                            Wh1, bh1, Wh2, bh2, ln1g, ln1b,
                                            Wm1, bm1, Wm2, bm2, ln2g, ln2b,
                                            (float*)d_out);

  hipMemcpyAsync((float*)d_out + (size_t)N_PROT * 128, pvec,
                 (size_t)N_PROT * 12 * sizeof(float), hipMemcpyDeviceToDevice, stream);
}